// Round 12
// baseline (2307.917 us; speedup 1.0000x reference)
//
#include <hip/hip_runtime.h>

#define NNODES 50000
#define NEDGES 1600000
#define F 128

#define NB 1024       // buckets (one agg block each)
#define BSH 49        // nodes per bucket (1024*49 = 50176 >= 50000)
#define BCAP 1840     // slots per bucket (mean 1562.5, +7 sigma)
#define EPT 10        // edges per thread in bucketA (625 * 2560 = 1600000 exactly)

#define PREP_A 625    // bucketA blocks
#define PREP_CVT 512  // cvt blocks
#define PREP_W 16     // wprep blocks

typedef __attribute__((ext_vector_type(8))) short bf16x8;
typedef __attribute__((ext_vector_type(4))) float f32x4;

__device__ inline unsigned short f2bf(float f) {
    union { float f; unsigned u; } v; v.f = f;
    unsigned r = v.u + 0x7FFF + ((v.u >> 16) & 1);  // RNE
    return (unsigned short)(r >> 16);
}
__device__ inline float2 up2(ushort2 h) {
    union { unsigned u; float f; } a, b;
    a.u = ((unsigned)h.x) << 16; b.u = ((unsigned)h.y) << 16;
    return make_float2(a.f, b.f);
}
__device__ inline float b2f(unsigned short h) {
    union { unsigned u; float f; } a;
    a.u = ((unsigned)h) << 16;
    return a.f;
}

// ---------------- merged prep: bucketA | cvt_bf16 | wprep ----------------
// Roles by blockIdx.x:  [0,625) bucketA,  [625,1137) cvt,  [1137,1153) wprep.
// gcnt must be zeroed (hipMemsetAsync) before this kernel.
__global__ __launch_bounds__(256) void prep(const float* __restrict__ x,
                                            const int* __restrict__ src,
                                            const int* __restrict__ dst,
                                            const float* __restrict__ W1,
                                            const float* __restrict__ W2,
                                            unsigned short* __restrict__ xb,
                                            unsigned short* __restrict__ Wf1,
                                            unsigned short* __restrict__ Wf2,
                                            unsigned* __restrict__ E1,
                                            int* __restrict__ gcnt) {
    const int bid = blockIdx.x;
    const int t = threadIdx.x;
    if (bid < PREP_A) {
        // ---- bucketA: multi-split edges into 1024 buckets ----
        // rec = (src << 6) | (dst % BSH); bucket = dst / BSH.
        __shared__ unsigned hist[4][NB];
        __shared__ unsigned start[4][NB];
        const int w = t >> 6;
        for (int i = t; i < 4 * NB; i += 256) ((unsigned*)hist)[i] = 0;
        __syncthreads();
        const int base = bid * (256 * EPT);
        unsigned rec[EPT]; int bkt[EPT]; unsigned rnk[EPT];
#pragma unroll
        for (int k = 0; k < EPT; ++k) {
            const int i = base + k * 256 + t;  // coalesced
            const int s = src[i], d = dst[i];
            const int b = d / BSH;             // const divide -> magic mul
            rec[k] = ((unsigned)s << 6) | (unsigned)(d - b * BSH);
            bkt[k] = b;
            rnk[k] = atomicAdd(&hist[w][b], 1u);
        }
        __syncthreads();
        for (int b = t; b < NB; b += 256) {
            const unsigned h0 = hist[0][b], h1 = hist[1][b], h2 = hist[2][b], h3 = hist[3][b];
            const unsigned tot = h0 + h1 + h2 + h3;
            const unsigned g = tot ? (unsigned)atomicAdd(&gcnt[b], (int)tot) : 0u;
            start[0][b] = g;
            start[1][b] = g + h0;
            start[2][b] = g + h0 + h1;
            start[3][b] = g + h0 + h1 + h2;
        }
        __syncthreads();
#pragma unroll
        for (int k = 0; k < EPT; ++k) {
            const unsigned p = start[w][bkt[k]] + rnk[k];
            if (p < BCAP) E1[(size_t)bkt[k] * BCAP + p] = rec[k];
        }
    } else if (bid < PREP_A + PREP_CVT) {
        // ---- cvt: f32 -> bf16 feature conversion ----
        const int n4 = NNODES * F / 4;
        const float4* in = (const float4*)x;
        ushort4* out = (ushort4*)xb;
        int i = (bid - PREP_A) * 256 + t;
        const int stride = PREP_CVT * 256;
        for (; i < n4; i += stride) {
            float4 v = in[i];
            ushort4 o;
            o.x = f2bf(v.x); o.y = f2bf(v.y); o.z = f2bf(v.z); o.w = f2bf(v.w);
            out[i] = o;
        }
    } else {
        // ---- wprep: pack W1,W2 into MFMA B-fragment order ----
        int id = (bid - PREP_A - PREP_CVT) * 256 + t;  // 0..4095
        const float* W = (id < 2048) ? W1 : W2;
        unsigned short* Wf = (id < 2048) ? Wf1 : Wf2;
        id &= 2047;
        const int l = id & 63, nn = (id >> 6) & 7, s = id >> 9;
        const int c = nn * 16 + (l & 15);
        const int k0 = s * 32 + (l >> 4) * 8;
        ushort4 lo, hi;
        lo.x = f2bf(W[(k0 + 0) * F + c]); lo.y = f2bf(W[(k0 + 1) * F + c]);
        lo.z = f2bf(W[(k0 + 2) * F + c]); lo.w = f2bf(W[(k0 + 3) * F + c]);
        hi.x = f2bf(W[(k0 + 4) * F + c]); hi.y = f2bf(W[(k0 + 5) * F + c]);
        hi.z = f2bf(W[(k0 + 6) * F + c]); hi.w = f2bf(W[(k0 + 7) * F + c]);
        ushort4* p = (ushort4*)(Wf + (size_t)id * 8);
        p[0] = lo; p[1] = hi;
    }
}

// ---------------- aggregation v3: block-per-bucket LDS accumulate ----------
// Block b owns nodes [49b, 49b+49). Acc[49][129] f32 (stride 129 breaks the
// systematic bank alias). Init = self rows; stream E1 records (coalesced),
// gather h[src] rows (16 in flight), ds_add_f32 into the dst row; writeback.
__global__ __launch_bounds__(256) void agg_acc(const ushort2* __restrict__ h,
                                               const unsigned* __restrict__ E1,
                                               const int* __restrict__ gcnt,
                                               ushort2* __restrict__ S, int n) {
    __shared__ float Acc[BSH][129];
    const int b = blockIdx.x, t = threadIdx.x;
    const int wave = t >> 6, lane = t & 63;
    const int node0 = b * BSH;
    for (int idx = t; idx < BSH * 64; idx += 256) {
        const int r = idx >> 6, l = idx & 63;
        const int node = node0 + r;
        float2 v = make_float2(0.f, 0.f);
        if (node < n) v = up2(h[(size_t)node * 64 + l]);
        Acc[r][2 * l] = v.x;
        Acc[r][2 * l + 1] = v.y;
    }
    __syncthreads();
    const int ne = min(gcnt[b], BCAP);
    const unsigned* E = E1 + (size_t)b * BCAP;
    const int ce = (ne + 3) >> 2;
    const int e0 = wave * ce, e1 = min(ne, e0 + ce);
    for (int base = e0; base < e1; base += 64) {
        const int cnt = min(64, e1 - base);
        const unsigned myrec = (base + lane < e1) ? E[base + lane] : 0u;
        int i = 0;
        for (; i + 16 <= cnt; i += 16) {
            float2 v[16]; int dl[16];
#pragma unroll
            for (int k = 0; k < 16; ++k) {
                const unsigned r = __shfl(myrec, i + k);
                dl[k] = (int)(r & 63u);
                v[k] = up2(h[(size_t)(r >> 6) * 64 + lane]);
            }
#pragma unroll
            for (int k = 0; k < 16; ++k) {
                atomicAdd(&Acc[dl[k]][2 * lane], v[k].x);
                atomicAdd(&Acc[dl[k]][2 * lane + 1], v[k].y);
            }
        }
        for (; i < cnt; ++i) {
            const unsigned r = __shfl(myrec, i);
            const float2 v = up2(h[(size_t)(r >> 6) * 64 + lane]);
            atomicAdd(&Acc[(int)(r & 63u)][2 * lane], v.x);
            atomicAdd(&Acc[(int)(r & 63u)][2 * lane + 1], v.y);
        }
    }
    __syncthreads();
    for (int idx = t; idx < BSH * 64; idx += 256) {
        const int r = idx >> 6, l = idx & 63;
        const int node = node0 + r;
        if (node < n) {
            ushort2 o;
            o.x = f2bf(Acc[r][2 * l]);
            o.y = f2bf(Acc[r][2 * l + 1]);
            S[(size_t)node * 64 + l] = o;
        }
    }
}

// ---------------- MFMA MLP: Hb = relu?(Sb @ W + b)  [M=n, N=128, K=128] -----
__global__ __launch_bounds__(256) void mlp_mfma(const unsigned short* __restrict__ Sb,
                                                const unsigned short* __restrict__ Wfrag,
                                                const float* __restrict__ bias,
                                                unsigned short* __restrict__ Hb,
                                                int n, int relu) {
    const int wave = threadIdx.x >> 6, lane = threadIdx.x & 63;
    const int base = blockIdx.x * 64 + wave * 16;
    const int r16 = lane & 15, hi = lane >> 4;
    int arow = base + r16;
    if (arow >= n) arow = n - 1;  // clamp loads; stores masked below
    const unsigned short* Arow = Sb + (size_t)arow * F;

    f32x4 acc[8];
#pragma unroll
    for (int i = 0; i < 8; ++i) acc[i] = (f32x4){0.f, 0.f, 0.f, 0.f};

#pragma unroll
    for (int s = 0; s < 4; ++s) {
        const bf16x8 a = *(const bf16x8*)(Arow + s * 32 + hi * 8);
#pragma unroll
        for (int nn = 0; nn < 8; ++nn) {
            const bf16x8 b = *(const bf16x8*)(Wfrag + ((size_t)(s * 8 + nn) * 64 + lane) * 8);
            acc[nn] = __builtin_amdgcn_mfma_f32_16x16x32_bf16(a, b, acc[nn], 0, 0, 0);
        }
    }

#pragma unroll
    for (int nn = 0; nn < 8; ++nn) {
        const int col = nn * 16 + r16;
        const float bv = bias[col];
#pragma unroll
        for (int r = 0; r < 4; ++r) {
            const int row = base + hi * 4 + r;
            if (row < n) {
                float v = acc[nn][r] + bv;
                if (relu) v = fmaxf(v, 0.f);
                Hb[(size_t)row * F + col] = f2bf(v);
            }
        }
    }
}

// ---------------- layer-3 transform first (linearity): y = h @ W3 ----------
__global__ __launch_bounds__(256) void head_t(const unsigned short* __restrict__ Hb,
                                              const float4* __restrict__ W3,
                                              float2* __restrict__ y, int n) {
    const int wid = (blockIdx.x * blockDim.x + threadIdx.x) >> 6;
    const int lane = threadIdx.x & 63;
    if (wid >= n) return;
    const unsigned short* hp = Hb + (size_t)wid * F + lane * 2;
    const float hx = b2f(hp[0]), hy = b2f(hp[1]);
    const float4 w = W3[lane];
    float a0 = hx * w.x + hy * w.z;
    float a1 = hx * w.y + hy * w.w;
#pragma unroll
    for (int o = 32; o; o >>= 1) {
        a0 += __shfl_xor(a0, o);
        a1 += __shfl_xor(a1, o);
    }
    if (lane == 0) y[wid] = make_float2(a0, a1);
}

// ---------------- layer-3 streaming aggregation on 2-dim y ------------------
// Block per bucket: out[i] = y[i] + sum y[src] + b3.
__global__ __launch_bounds__(256) void agg3s(const float2* __restrict__ y,
                                             const unsigned* __restrict__ E1,
                                             const int* __restrict__ gcnt,
                                             const float* __restrict__ b3,
                                             float2* __restrict__ out, int n) {
    __shared__ float A0[BSH], A1[BSH];
    const int b = blockIdx.x, t = threadIdx.x;
    if (t < BSH) { A0[t] = 0.f; A1[t] = 0.f; }
    __syncthreads();
    const int ne = min(gcnt[b], BCAP);
    const unsigned* E = E1 + (size_t)b * BCAP;
    for (int e = t; e < ne; e += 256) {
        const unsigned rec = E[e];
        const float2 v = y[rec >> 6];
        atomicAdd(&A0[rec & 63u], v.x);
        atomicAdd(&A1[rec & 63u], v.y);
    }
    __syncthreads();
    if (t < BSH) {
        const int node = b * BSH + t;
        if (node < n) {
            const float2 s = y[node];
            out[node] = make_float2(s.x + A0[t] + b3[0], s.y + A1[t] + b3[1]);
        }
    }
}

extern "C" void kernel_launch(void* const* d_in, const int* in_sizes, int n_in,
                              void* d_out, int out_size, void* d_ws, size_t ws_size,
                              hipStream_t stream) {
    const float* x  = (const float*)d_in[0];
    const int* ei   = (const int*)d_in[1];
    const int* src  = ei;
    const int* dst  = ei + NEDGES;
    const float* W1 = (const float*)d_in[2];
    const float* b1 = (const float*)d_in[3];
    const float* W2 = (const float*)d_in[4];
    const float* b2 = (const float*)d_in[5];
    const float* W3 = (const float*)d_in[6];
    const float* b3 = (const float*)d_in[7];
    float* out = (float*)d_out;

    char* ws = (char*)d_ws;
    const size_t featB = (size_t)NNODES * F * 2;  // 12.8 MB
    unsigned short* xb = (unsigned short*)ws;                 // bf16 x; reused for H2
    unsigned short* Sb = (unsigned short*)(ws + featB);       // aggregated (bf16)
    unsigned short* Hb = (unsigned short*)(ws + 2 * featB);   // layer-1 output
    char* p = ws + 3 * featB;
    float* y3 = (float*)p;                 p += (size_t)NNODES * 2 * 4 + 256;
    unsigned short* Wf1 = (unsigned short*)p; p += 2048 * 8 * 2;
    unsigned short* Wf2 = (unsigned short*)p; p += 2048 * 8 * 2;
    unsigned* E1 = (unsigned*)p;           p += (size_t)NB * BCAP * 4;
    int* gcnt = (int*)p;                   p += NB * 4 + 256;

    // ---- prep (gcnt must be zero before prep's bucketA role) ----
    hipMemsetAsync(gcnt, 0, NB * sizeof(int), stream);
    prep<<<PREP_A + PREP_CVT + PREP_W, 256, 0, stream>>>(x, src, dst, W1, W2,
                                                         xb, Wf1, Wf2, E1, gcnt);

    const int mlpBlocks = (NNODES + 63) / 64;

    // ---- layer 1 ----
    agg_acc<<<NB, 256, 0, stream>>>((const ushort2*)xb, E1, gcnt, (ushort2*)Sb, NNODES);
    mlp_mfma<<<mlpBlocks, 256, 0, stream>>>(Sb, Wf1, b1, Hb, NNODES, 1);

    // ---- layer 2 ----
    agg_acc<<<NB, 256, 0, stream>>>((const ushort2*)Hb, E1, gcnt, (ushort2*)Sb, NNODES);
    mlp_mfma<<<mlpBlocks, 256, 0, stream>>>(Sb, Wf2, b2, xb, NNODES, 1);

    // ---- layer 3: transform first (linearity), then streaming 2-dim agg ----
    head_t<<<(NNODES + 3) / 4, 256, 0, stream>>>(xb, (const float4*)W3, (float2*)y3, NNODES);
    agg3s<<<NB, 256, 0, stream>>>((const float2*)y3, E1, gcnt, b3, (float2*)out, NNODES);
}

// Round 14
// 252.788 us; speedup vs baseline: 9.1299x; 9.1299x over previous
//
#include <hip/hip_runtime.h>

#define NNODES 50000
#define NEDGES 1600000
#define F 128

#define NB 512        // coarse buckets
#define BSH 98        // nodes per bucket (512*98 = 50176 >= 50000)
#define BCAP 3500     // slots per bucket (mean 3125, +6.7 sigma)
#define EPT 10        // edges per thread in bucketA (625 * 2560 = 1600000 exactly)

#define PREP_A 625    // bucketA blocks
#define PREP_CVT 512  // cvt blocks
#define PREP_W 16     // wprep blocks

typedef __attribute__((ext_vector_type(8))) short bf16x8;
typedef __attribute__((ext_vector_type(4))) float f32x4;

__device__ inline unsigned short f2bf(float f) {
    union { float f; unsigned u; } v; v.f = f;
    unsigned r = v.u + 0x7FFF + ((v.u >> 16) & 1);  // RNE
    return (unsigned short)(r >> 16);
}
__device__ inline float2 up2(ushort2 h) {
    union { unsigned u; float f; } a, b;
    a.u = ((unsigned)h.x) << 16; b.u = ((unsigned)h.y) << 16;
    return make_float2(a.f, b.f);
}
__device__ inline float b2f(unsigned short h) {
    union { unsigned u; float f; } a;
    a.u = ((unsigned)h) << 16;
    return a.f;
}

// ---------------- merged prep: bucketA | cvt_bf16 | wprep ----------------
// Roles by blockIdx.x:  [0,625) bucketA,  [625,1137) cvt,  [1137,1153) wprep.
// gcnt must be zeroed (hipMemsetAsync) before this kernel.
__global__ __launch_bounds__(256) void prep(const float* __restrict__ x,
                                            const int* __restrict__ src,
                                            const int* __restrict__ dst,
                                            const float* __restrict__ W1,
                                            const float* __restrict__ W2,
                                            unsigned short* __restrict__ xb,
                                            unsigned short* __restrict__ Wf1,
                                            unsigned short* __restrict__ Wf2,
                                            unsigned* __restrict__ E1,
                                            int* __restrict__ gcnt) {
    const int bid = blockIdx.x;
    const int t = threadIdx.x;
    if (bid < PREP_A) {
        // ---- bucketA: multi-split edges into 512 coarse buckets ----
        // rec = (src << 7) | (dst % BSH); bucket = dst / BSH.
        __shared__ unsigned hist[4][NB];
        __shared__ unsigned start[4][NB];
        const int w = t >> 6;
        for (int i = t; i < 4 * NB; i += 256) ((unsigned*)hist)[i] = 0;
        __syncthreads();
        const int base = bid * (256 * EPT);
        unsigned rec[EPT]; int bkt[EPT]; unsigned rnk[EPT];
#pragma unroll
        for (int k = 0; k < EPT; ++k) {
            const int i = base + k * 256 + t;  // coalesced
            const int s = src[i], d = dst[i];
            const int b = d / BSH;             // const divide -> magic mul
            rec[k] = ((unsigned)s << 7) | (unsigned)(d - b * BSH);
            bkt[k] = b;
            rnk[k] = atomicAdd(&hist[w][b], 1u);
        }
        __syncthreads();
        for (int b = t; b < NB; b += 256) {
            const unsigned h0 = hist[0][b], h1 = hist[1][b], h2 = hist[2][b], h3 = hist[3][b];
            const unsigned tot = h0 + h1 + h2 + h3;
            const unsigned g = tot ? (unsigned)atomicAdd(&gcnt[b], (int)tot) : 0u;
            start[0][b] = g;
            start[1][b] = g + h0;
            start[2][b] = g + h0 + h1;
            start[3][b] = g + h0 + h1 + h2;
        }
        __syncthreads();
#pragma unroll
        for (int k = 0; k < EPT; ++k) {
            const unsigned p = start[w][bkt[k]] + rnk[k];
            if (p < BCAP) E1[(size_t)bkt[k] * BCAP + p] = rec[k];
        }
    } else if (bid < PREP_A + PREP_CVT) {
        // ---- cvt: f32 -> bf16 feature conversion ----
        const int n4 = NNODES * F / 4;
        const float4* in = (const float4*)x;
        ushort4* out = (ushort4*)xb;
        int i = (bid - PREP_A) * 256 + t;
        const int stride = PREP_CVT * 256;
        for (; i < n4; i += stride) {
            float4 v = in[i];
            ushort4 o;
            o.x = f2bf(v.x); o.y = f2bf(v.y); o.z = f2bf(v.z); o.w = f2bf(v.w);
            out[i] = o;
        }
    } else {
        // ---- wprep: pack W1,W2 into MFMA B-fragment order ----
        int id = (bid - PREP_A - PREP_CVT) * 256 + t;  // 0..4095
        const float* W = (id < 2048) ? W1 : W2;
        unsigned short* Wf = (id < 2048) ? Wf1 : Wf2;
        id &= 2047;
        const int l = id & 63, nn = (id >> 6) & 7, s = id >> 9;
        const int c = nn * 16 + (l & 15);
        const int k0 = s * 32 + (l >> 4) * 8;
        ushort4 lo, hi;
        lo.x = f2bf(W[(k0 + 0) * F + c]); lo.y = f2bf(W[(k0 + 1) * F + c]);
        lo.z = f2bf(W[(k0 + 2) * F + c]); lo.w = f2bf(W[(k0 + 3) * F + c]);
        hi.x = f2bf(W[(k0 + 4) * F + c]); hi.y = f2bf(W[(k0 + 5) * F + c]);
        hi.z = f2bf(W[(k0 + 6) * F + c]); hi.w = f2bf(W[(k0 + 7) * F + c]);
        ushort4* p = (ushort4*)(Wf + (size_t)id * 8);
        p[0] = lo; p[1] = hi;
    }
}

// ---------------- phase B: in-LDS counting sort per bucket -> exact CSR -----
__global__ __launch_bounds__(256) void bucketB(const unsigned* __restrict__ E1,
                                               const int* __restrict__ gcnt,
                                               int* __restrict__ off,
                                               unsigned short* __restrict__ ssrc) {
    __shared__ int cnt[BSH];
    __shared__ int cur[BSH];
    __shared__ int wtot[4];
    __shared__ int bst[NB];
    const int b = blockIdx.x, t = threadIdx.x;
    // one-wave exclusive scan of the 512 bucket counts (8 per lane)
    if (t < 64) {
        int a[8]; int s = 0;
#pragma unroll
        for (int k = 0; k < 8; ++k) { a[k] = gcnt[t * 8 + k]; s += a[k]; }
        int inc = s;
#pragma unroll
        for (int o = 1; o <= 32; o <<= 1) {
            int u = __shfl_up(inc, o);
            if (t >= o) inc += u;
        }
        int e = inc - s;
#pragma unroll
        for (int k = 0; k < 8; ++k) { bst[t * 8 + k] = e; e += a[k]; }
    }
    for (int i = t; i < BSH; i += 256) cnt[i] = 0;
    __syncthreads();
    const int ne = min(gcnt[b], BCAP);
    const int ebase = bst[b];
    const unsigned* E = E1 + (size_t)b * BCAP;
    for (int i = t; i < ne; i += 256) atomicAdd(&cnt[E[i] & 127], 1);
    __syncthreads();
    // exclusive scan of cnt[0..BSH), 1 element per thread (BSH=98 < 256)
    const int val = (t < BSH) ? cnt[t] : 0;
    int inc = val;
    const int lane = t & 63, w = t >> 6;
#pragma unroll
    for (int o = 1; o <= 32; o <<= 1) {
        int u = __shfl_up(inc, o);
        if (lane >= o) inc += u;
    }
    if (lane == 63) wtot[w] = inc;
    __syncthreads();
    int woff = 0;
    for (int k = 0; k < w; ++k) woff += wtot[k];  // w <= 3
    const int excl = woff + inc - val;
    if (t < BSH) {
        cur[t] = excl;
        const int n = b * BSH + t;
        if (n < NNODES) off[n] = ebase + excl;
    }
    if (b == NB - 1 && t == 0) off[NNODES] = NEDGES;
    __syncthreads();
    for (int i = t; i < ne; i += 256) {
        const unsigned rec = E[i];
        const int r = atomicAdd(&cur[rec & 127], 1);
        ssrc[ebase + r] = (unsigned short)(rec >> 7);
    }
}

// ---------------- aggregation (bf16): S[i] = h[i] + sum h[ssrc[e]] ------
// One wave per node (1-wave blocks, grid = n). Lane l holds feats 2l,2l+1.
// Coalesced index load per 64 edges + shfl broadcast; 16 gathers in flight.
// (R10-verified version — do not touch.)
__global__ __launch_bounds__(64) void agg_bf16(const ushort2* __restrict__ h,
                                               const int* __restrict__ off,
                                               const unsigned short* __restrict__ ssrc,
                                               ushort2* __restrict__ S, int n) {
    const int wid = blockIdx.x;
    const int lane = threadIdx.x;
    const int e0 = off[wid], e1 = off[wid + 1];
    float2 acc = up2(h[(size_t)wid * 64 + lane]);
    for (int base = e0; base < e1; base += 64) {
        const int cnt = min(64, e1 - base);
        const int myidx = (base + lane < e1) ? (int)ssrc[base + lane] : 0;
        int i = 0;
        for (; i + 16 <= cnt; i += 16) {
            float2 v[16];
#pragma unroll
            for (int k = 0; k < 16; ++k) {
                const int s = __shfl(myidx, i + k);
                v[k] = up2(h[(size_t)s * 64 + lane]);
            }
            float x0 = 0.f, y0 = 0.f;
#pragma unroll
            for (int k = 0; k < 16; ++k) { x0 += v[k].x; y0 += v[k].y; }
            acc.x += x0; acc.y += y0;
        }
        for (; i + 4 <= cnt; i += 4) {
            const int s0 = __shfl(myidx, i + 0), s1 = __shfl(myidx, i + 1);
            const int s2 = __shfl(myidx, i + 2), s3 = __shfl(myidx, i + 3);
            const float2 v0 = up2(h[(size_t)s0 * 64 + lane]);
            const float2 v1 = up2(h[(size_t)s1 * 64 + lane]);
            const float2 v2 = up2(h[(size_t)s2 * 64 + lane]);
            const float2 v3 = up2(h[(size_t)s3 * 64 + lane]);
            acc.x += (v0.x + v1.x) + (v2.x + v3.x);
            acc.y += (v0.y + v1.y) + (v2.y + v3.y);
        }
        for (; i < cnt; ++i) {
            const int s = __shfl(myidx, i);
            const float2 v = up2(h[(size_t)s * 64 + lane]);
            acc.x += v.x;
            acc.y += v.y;
        }
    }
    ushort2 o;
    o.x = f2bf(acc.x); o.y = f2bf(acc.y);
    S[(size_t)wid * 64 + lane] = o;
}

// ---------------- MFMA MLP (layer 1): Hb = relu(Sb @ W + b) ----------------
__global__ __launch_bounds__(256) void mlp_mfma(const unsigned short* __restrict__ Sb,
                                                const unsigned short* __restrict__ Wfrag,
                                                const float* __restrict__ bias,
                                                unsigned short* __restrict__ Hb,
                                                int n) {
    const int wave = threadIdx.x >> 6, lane = threadIdx.x & 63;
    const int base = blockIdx.x * 64 + wave * 16;
    const int r16 = lane & 15, hi = lane >> 4;
    int arow = base + r16;
    if (arow >= n) arow = n - 1;  // clamp loads; stores masked below
    const unsigned short* Arow = Sb + (size_t)arow * F;

    f32x4 acc[8];
#pragma unroll
    for (int i = 0; i < 8; ++i) acc[i] = (f32x4){0.f, 0.f, 0.f, 0.f};

#pragma unroll
    for (int s = 0; s < 4; ++s) {
        const bf16x8 a = *(const bf16x8*)(Arow + s * 32 + hi * 8);
#pragma unroll
        for (int nn = 0; nn < 8; ++nn) {
            const bf16x8 b = *(const bf16x8*)(Wfrag + ((size_t)(s * 8 + nn) * 64 + lane) * 8);
            acc[nn] = __builtin_amdgcn_mfma_f32_16x16x32_bf16(a, b, acc[nn], 0, 0, 0);
        }
    }

#pragma unroll
    for (int nn = 0; nn < 8; ++nn) {
        const int col = nn * 16 + r16;
        const float bv = bias[col];
#pragma unroll
        for (int r = 0; r < 4; ++r) {
            const int row = base + hi * 4 + r;
            if (row < n) {
                Hb[(size_t)row * F + col] = f2bf(fmaxf(acc[nn][r] + bv, 0.f));
            }
        }
    }
}

// ---------------- MFMA MLP (layer 2) + fused head: y = relu(Sb@W+b) @ W3 ----
// C/D mapping: thread (r16=lane&15, hi=lane>>4) holds col=nn*16+r16,
// row=base+hi*4+r. Head sum over 128 cols = over nn (in-thread) x r16 (16-lane
// shfl_xor reduce, bits 0..3). Lane r16==0 of each hi-group writes 4 rows.
__global__ __launch_bounds__(256) void mlp_head(const unsigned short* __restrict__ Sb,
                                                const unsigned short* __restrict__ Wfrag,
                                                const float* __restrict__ bias,
                                                const float* __restrict__ W3,
                                                float2* __restrict__ y, int n) {
    const int wave = threadIdx.x >> 6, lane = threadIdx.x & 63;
    const int base = blockIdx.x * 64 + wave * 16;
    const int r16 = lane & 15, hi = lane >> 4;
    int arow = base + r16;
    if (arow >= n) arow = n - 1;
    const unsigned short* Arow = Sb + (size_t)arow * F;

    f32x4 acc[8];
#pragma unroll
    for (int i = 0; i < 8; ++i) acc[i] = (f32x4){0.f, 0.f, 0.f, 0.f};

#pragma unroll
    for (int s = 0; s < 4; ++s) {
        const bf16x8 a = *(const bf16x8*)(Arow + s * 32 + hi * 8);
#pragma unroll
        for (int nn = 0; nn < 8; ++nn) {
            const bf16x8 b = *(const bf16x8*)(Wfrag + ((size_t)(s * 8 + nn) * 64 + lane) * 8);
            acc[nn] = __builtin_amdgcn_mfma_f32_16x16x32_bf16(a, b, acc[nn], 0, 0, 0);
        }
    }

    float y0[4] = {0.f, 0.f, 0.f, 0.f}, y1[4] = {0.f, 0.f, 0.f, 0.f};
#pragma unroll
    for (int nn = 0; nn < 8; ++nn) {
        const int col = nn * 16 + r16;
        const float bv = bias[col];
        const float2 w3 = ((const float2*)W3)[col];
#pragma unroll
        for (int r = 0; r < 4; ++r) {
            const float v = fmaxf(acc[nn][r] + bv, 0.f);
            y0[r] += v * w3.x;
            y1[r] += v * w3.y;
        }
    }
#pragma unroll
    for (int r = 0; r < 4; ++r) {
#pragma unroll
        for (int o = 1; o <= 8; o <<= 1) {
            y0[r] += __shfl_xor(y0[r], o);
            y1[r] += __shfl_xor(y1[r], o);
        }
    }
    if (r16 == 0) {
#pragma unroll
        for (int r = 0; r < 4; ++r) {
            const int row = base + hi * 4 + r;
            if (row < n) y[row] = make_float2(y0[r], y1[r]);
        }
    }
}

// ---------------- layer-3 aggregation on 2-dim y: out = y + agg(y) + b3 -----
__global__ __launch_bounds__(256) void agg3(const float2* __restrict__ y,
                                            const int* __restrict__ off,
                                            const unsigned short* __restrict__ ssrc,
                                            const float* __restrict__ b3,
                                            float2* __restrict__ out, int n) {
    const int i = blockIdx.x * blockDim.x + threadIdx.x;
    if (i >= n) return;
    float2 acc = y[i];
    const int e1 = off[i + 1];
    for (int e = off[i]; e < e1; ++e) {
        const float2 v = y[ssrc[e]];
        acc.x += v.x;
        acc.y += v.y;
    }
    out[i] = make_float2(acc.x + b3[0], acc.y + b3[1]);
}

extern "C" void kernel_launch(void* const* d_in, const int* in_sizes, int n_in,
                              void* d_out, int out_size, void* d_ws, size_t ws_size,
                              hipStream_t stream) {
    const float* x  = (const float*)d_in[0];
    const int* ei   = (const int*)d_in[1];
    const int* src  = ei;
    const int* dst  = ei + NEDGES;
    const float* W1 = (const float*)d_in[2];
    const float* b1 = (const float*)d_in[3];
    const float* W2 = (const float*)d_in[4];
    const float* b2 = (const float*)d_in[5];
    const float* W3 = (const float*)d_in[6];
    const float* b3 = (const float*)d_in[7];
    float* out = (float*)d_out;

    char* ws = (char*)d_ws;
    const size_t featB = (size_t)NNODES * F * 2;  // 12.8 MB
    unsigned short* xb = (unsigned short*)ws;                 // bf16 x
    unsigned short* Sb = (unsigned short*)(ws + featB);       // aggregated (bf16)
    unsigned short* Hb = (unsigned short*)(ws + 2 * featB);   // layer-1 output
    char* p = ws + 3 * featB;
    float* y3 = (float*)p;                 p += (size_t)NNODES * 2 * 4 + 256;
    unsigned short* Wf1 = (unsigned short*)p; p += 2048 * 8 * 2;
    unsigned short* Wf2 = (unsigned short*)p; p += 2048 * 8 * 2;
    unsigned* E1 = (unsigned*)p;           p += (size_t)NB * BCAP * 4;
    int* gcnt = (int*)p;                   p += NB * 4 + 256;
    int* off = (int*)p;                    p += (size_t)(NNODES + 1) * 4 + 256;
    unsigned short* ssrc = (unsigned short*)p;

    // ---- prep (gcnt must be zero before prep's bucketA role) ----
    hipMemsetAsync(gcnt, 0, NB * sizeof(int), stream);
    prep<<<PREP_A + PREP_CVT + PREP_W, 256, 0, stream>>>(x, src, dst, W1, W2,
                                                         xb, Wf1, Wf2, E1, gcnt);
    bucketB<<<NB, 256, 0, stream>>>(E1, gcnt, off, ssrc);

    const int mlpBlocks = (NNODES + 63) / 64;

    // ---- layer 1 ----
    agg_bf16<<<NNODES, 64, 0, stream>>>((const ushort2*)xb, off, ssrc, (ushort2*)Sb, NNODES);
    mlp_mfma<<<mlpBlocks, 256, 0, stream>>>(Sb, Wf1, b1, Hb, NNODES);

    // ---- layer 2 (+ fused layer-3 transform) ----
    agg_bf16<<<NNODES, 64, 0, stream>>>((const ushort2*)Hb, off, ssrc, (ushort2*)Sb, NNODES);
    mlp_head<<<mlpBlocks, 256, 0, stream>>>(Sb, Wf2, b2, W3, (float2*)y3, NNODES);

    // ---- layer 3: 2-dim aggregation ----
    agg3<<<(NNODES + 255) / 256, 256, 0, stream>>>((const float2*)y3, off, ssrc, b3, (float2*)out, NNODES);
}